// Round 4
// baseline (178.325 us; speedup 1.0000x reference)
//
#include <hip/hip_runtime.h>
#include <math.h>

typedef float f32x4 __attribute__((ext_vector_type(4)));
typedef __bf16 bf16x8 __attribute__((ext_vector_type(8)));

#define MFMA16(a, b, c) __builtin_amdgcn_mfma_f32_16x16x32_bf16((a), (b), (c), 0, 0, 0)

constexpr int Bsz = 2, Nseq = 2048, Dm = 1024, Hh = 16, HDim = 64, F3 = 192;
constexpr int Mrows = Bsz * Nseq;   // 4096
constexpr int NC = Hh * F3;         // 3072 output cols
constexpr float QSCALE = 0.125f * 1.4426950408889634f;

__device__ inline void load_lds16(const void* g, void* l) {
    __builtin_amdgcn_global_load_lds((const __attribute__((address_space(1))) void*)g,
                                     (__attribute__((address_space(3))) void*)l, 16, 0, 0);
}

#define FENCE asm volatile("" ::: "memory")
#define BARRIER do { FENCE; __builtin_amdgcn_s_barrier(); FENCE; } while (0)
#define WAIT6 asm volatile("s_waitcnt vmcnt(6)" ::: "memory")

// ---------------- kernel 0: x fp32 -> bf16 ----------------
__global__ __launch_bounds__(256) void conv_x_kernel(const float* __restrict__ x,
                                                     __bf16* __restrict__ xb) {
    int i = blockIdx.x * 256 + threadIdx.x;
    const float4* xv = reinterpret_cast<const float4*>(x);
    float4 a = xv[2 * i];
    float4 b = xv[2 * i + 1];
    bf16x8 o = {(__bf16)a.x, (__bf16)a.y, (__bf16)a.z, (__bf16)a.w,
                (__bf16)b.x, (__bf16)b.y, (__bf16)b.z, (__bf16)b.w};
    *reinterpret_cast<bf16x8*>(xb + 8 * i) = o;
}

// ---------------- kernel 1: W fp32 [h][d][c] -> bf16 transposed [h][c][d] ----------------
__global__ __launch_bounds__(256) void conv_w_kernel(const float* __restrict__ w,
                                                     __bf16* __restrict__ wt) {
    __shared__ __bf16 tile[32][66];
    int h = blockIdx.z, d0 = blockIdx.x * 32, c0 = blockIdx.y * 64;
    for (int i = threadIdx.x; i < 32 * 64; i += 256) {
        int di = i >> 6, cj = i & 63;
        tile[di][cj] = (__bf16)w[(size_t)(h * Dm + d0 + di) * F3 + c0 + cj];
    }
    __syncthreads();
    for (int i = threadIdx.x; i < 32 * 64; i += 256) {
        int ci = i >> 5, dj = i & 31;
        wt[(size_t)(h * F3 + c0 + ci) * Dm + d0 + dj] = tile[dj][ci];
    }
}

// ---------------- kernel 2a: proj as 256x256 8-phase pipelined GEMM (CONTROL: unchanged) ---
__global__ __launch_bounds__(512, 2) void gemm_proj(const __bf16* __restrict__ xb,
                                                    const __bf16* __restrict__ wt,
                                                    const float* __restrict__ bias,
                                                    __bf16* __restrict__ kbuf,
                                                    __bf16* __restrict__ qbuf,
                                                    __bf16* __restrict__ vt) {
    __shared__ __align__(16) __bf16 Ab[2][256 * 64];
    __shared__ __align__(16) __bf16 Bb[2][256 * 64];

    int flat = blockIdx.x;                       // 0..191
    int swz = (flat & 7) * 24 + (flat >> 3);     // bijective XCD swizzle (192 = 8*24)
    int bm = swz / 12, bn = swz % 12;            // 16 x 12 tile grid
    int r0 = bm * 256, n0 = bn * 256;

    int w = threadIdx.x >> 6, lane = threadIdx.x & 63;
    int col = lane & 15, quad = lane >> 4;
    int wm = w >> 2, wn = w & 3;

    f32x4 acc[8][4] = {};
    bf16x8 af[2][4];   // A quadrant, held across 2 phases (mh reused for nh=0,1)
    bf16x8 bfr[2][2];  // B quadrant, re-read each phase

    auto stageA = [&](int t, int s, int h) {
        int rl = lane >> 3;
        int cg = (lane & 7) ^ rl;
#pragma unroll
        for (int r = 0; r < 2; r++) {
            int rowb = r * 128 + h * 64 + w * 8;           // multiple of 8
            load_lds16(xb + (size_t)(r0 + rowb + rl) * Dm + t * 64 + cg * 8,
                       &Ab[s][rowb * 64]);
        }
    };
    auto stageB = [&](int t, int s, int h) {
        int rl = lane >> 3;
        int cg = (lane & 7) ^ rl;
#pragma unroll
        for (int r = 0; r < 2; r++) {
            int rowb = ((w >> 2) + r * 2) * 64 + h * 32 + (w & 3) * 8;  // mult of 8
            load_lds16(wt + (size_t)(n0 + rowb + rl) * Dm + t * 64 + cg * 8,
                       &Bb[s][rowb * 64]);
        }
    };

    auto readA = [&](int s, int mh) {
#pragma unroll
        for (int ks = 0; ks < 2; ks++)
#pragma unroll
            for (int mt = 0; mt < 4; mt++) {
                int row = wm * 128 + mh * 64 + mt * 16 + col;
                af[ks][mt] = *reinterpret_cast<const bf16x8*>(
                    &Ab[s][row * 64 + (((ks * 4 + quad) ^ (row & 7)) * 8)]);
            }
    };
    auto readB = [&](int s, int nh) {
#pragma unroll
        for (int ks = 0; ks < 2; ks++)
#pragma unroll
            for (int nt = 0; nt < 2; nt++) {
                int row = wn * 64 + nh * 32 + nt * 16 + col;
                bfr[ks][nt] = *reinterpret_cast<const bf16x8*>(
                    &Bb[s][row * 64 + (((ks * 4 + quad) ^ (row & 7)) * 8)]);
            }
    };
    auto mfmaQ = [&](int mh, int nh) {
        __builtin_amdgcn_s_setprio(1);
#pragma unroll
        for (int ks = 0; ks < 2; ks++)
#pragma unroll
            for (int mt = 0; mt < 4; mt++)
#pragma unroll
                for (int nt = 0; nt < 2; nt++)
                    acc[mh * 4 + mt][nh * 2 + nt] =
                        MFMA16(af[ks][mt], bfr[ks][nt], acc[mh * 4 + mt][nh * 2 + nt]);
        __builtin_amdgcn_s_setprio(0);
    };

    stageA(0, 0, 0); stageB(0, 0, 0); stageA(0, 0, 1); stageB(0, 0, 1);
    stageA(1, 1, 0);
    stageB(1, 1, 0); stageA(1, 1, 1);
    WAIT6;
    BARRIER;

    for (int i = 0; i < 8; i++) {
        int t0 = 2 * i;
        int t2 = t0 + 2; if (t2 > 15) t2 = 15;
        int t3 = t0 + 3; if (t3 > 15) t3 = 15;

        readA(0, 0); readB(0, 0);
        stageB(t0 + 1, 1, 1);
        BARRIER; mfmaQ(0, 0); BARRIER;

        readB(0, 1);
        stageA(t2, 0, 0);
        BARRIER; mfmaQ(0, 1); BARRIER;

        readA(0, 1); readB(0, 0);
        BARRIER; mfmaQ(1, 0); BARRIER;

        readB(0, 1);
        stageB(t2, 0, 0); stageA(t2, 0, 1);
        WAIT6;
        BARRIER; mfmaQ(1, 1); BARRIER;

        readA(1, 0); readB(1, 0);
        stageB(t2, 0, 1);
        BARRIER; mfmaQ(0, 0); BARRIER;

        readB(1, 1);
        stageA(t3, 1, 0);
        BARRIER; mfmaQ(0, 1); BARRIER;

        readA(1, 1); readB(1, 0);
        BARRIER; mfmaQ(1, 0); BARRIER;

        readB(1, 1);
        stageB(t3, 1, 0); stageA(t3, 1, 1);
        WAIT6;
        BARRIER; mfmaQ(1, 1); BARRIER;
    }

#pragma unroll
    for (int nt = 0; nt < 4; nt++) {
        int g = n0 + wn * 64 + nt * 16 + col;
        int h = g / F3, c = g - h * F3;
        float bv = bias[g];
        bool isq = (c >= 64 && c < 128), isv = (c >= 128);
        int cd = c & 63;
#pragma unroll
        for (int mt = 0; mt < 8; mt++) {
#pragma unroll
            for (int rg = 0; rg < 4; rg++) {
                int r = r0 + wm * 128 + mt * 16 + quad * 4 + rg;
                int b = r >> 11, n = r & (Nseq - 1);
                float v = acc[mt][nt][rg] + bv;
                if (isq) v *= QSCALE;
                size_t bh = (size_t)(b * Hh + h);
                if (isv) vt[(bh * HDim + cd) * Nseq + n] = (__bf16)v;
                else ((isq) ? qbuf : kbuf)[(bh * Nseq + n) * HDim + cd] = (__bf16)v;
            }
        }
    }
}

// ---------------- kernel 2b: fallback proj if ws too small ----------------
__global__ __launch_bounds__(256) void proj_small(const float* __restrict__ x,
                                                  const __bf16* __restrict__ wt,
                                                  const float* __restrict__ bias,
                                                  __bf16* __restrict__ kbuf,
                                                  __bf16* __restrict__ qbuf,
                                                  __bf16* __restrict__ vt) {
    int h = blockIdx.y;
    int wave = threadIdx.x >> 6, lane = threadIdx.x & 63;
    int col = lane & 15, quad = lane >> 4;
    int r0 = blockIdx.x * 128 + wave * 32;

    f32x4 acc[12][2] = {};
    const float* xr0 = x + (size_t)(r0 + col) * Dm + quad * 8;
    const float* xr1 = xr0 + 16 * Dm;
    const __bf16* wbase = wt + (size_t)(h * F3 + col) * Dm + quad * 8;

    for (int k0 = 0; k0 < Dm; k0 += 32) {
        float4 a0lo = *reinterpret_cast<const float4*>(xr0 + k0);
        float4 a0hi = *reinterpret_cast<const float4*>(xr0 + k0 + 4);
        float4 a1lo = *reinterpret_cast<const float4*>(xr1 + k0);
        float4 a1hi = *reinterpret_cast<const float4*>(xr1 + k0 + 4);
        bf16x8 a0 = {(__bf16)a0lo.x, (__bf16)a0lo.y, (__bf16)a0lo.z, (__bf16)a0lo.w,
                     (__bf16)a0hi.x, (__bf16)a0hi.y, (__bf16)a0hi.z, (__bf16)a0hi.w};
        bf16x8 a1 = {(__bf16)a1lo.x, (__bf16)a1lo.y, (__bf16)a1lo.z, (__bf16)a1lo.w,
                     (__bf16)a1hi.x, (__bf16)a1hi.y, (__bf16)a1hi.z, (__bf16)a1hi.w};
#pragma unroll
        for (int ct = 0; ct < 12; ct++) {
            bf16x8 bf = *reinterpret_cast<const bf16x8*>(wbase + ct * 16 * Dm + k0);
            acc[ct][0] = MFMA16(a0, bf, acc[ct][0]);
            acc[ct][1] = MFMA16(a1, bf, acc[ct][1]);
        }
    }
#pragma unroll
    for (int ct = 0; ct < 12; ct++) {
        int c = ct * 16 + col;
        float bv = bias[h * F3 + c];
        int cd = c & 63;
        bool isq = (c >= 64 && c < 128), isv = (c >= 128);
#pragma unroll
        for (int rt = 0; rt < 2; rt++) {
#pragma unroll
            for (int rg = 0; rg < 4; rg++) {
                int r = r0 + rt * 16 + quad * 4 + rg;
                int b = r >> 11, n = r & (Nseq - 1);
                float v = acc[ct][rt][rg] + bv;
                if (isq) v *= QSCALE;
                size_t bh = (size_t)(b * Hh + h);
                if (isv) vt[(bh * HDim + cd) * Nseq + n] = (__bf16)v;
                else ((isq) ? qbuf : kbuf)[(bh * Nseq + n) * HDim + cd] = (__bf16)v;
            }
        }
    }
}

// ---------------- kernel 3: flash attention, adjacent-tile pairing ----------------
// Change vs previous round: block (bh, p) handles ADJACENT q-tiles 2p (waves 0-3)
// and 2p+1 (waves 4-7) instead of complementary (p, 31-p). loop_end = 128p+128
// covers both tiles' causal ranges; waves 0-3 are inactive for exactly ONE
// iteration (the last) instead of idling for (31-2p) iterations. Grid-wide
// active wave-iteration efficiency: 67% -> 97%; mean block critical path
// 24.5 -> 17 iterations. K/V staging traffic drops ~200 -> ~140 MB (L2-resident).
// Staging / swizzle / double-buffer / counted-vmcnt / math / epilogue unchanged.
__global__ __launch_bounds__(512) void attn_kernel(const __bf16* __restrict__ qbuf,
                                                   const __bf16* __restrict__ kbuf,
                                                   const __bf16* __restrict__ vt,
                                                   float* __restrict__ out) {
    __shared__ __align__(16) __bf16 Kb[2][64 * 64];    // [buf][key][dim], swizzled chunks
    __shared__ __align__(16) __bf16 Vb[2][64 * 64];    // [buf][dim][key], swizzled chunks
    __shared__ __align__(16) __bf16 plds[8][16][72];   // per-wave P tile, 2-way max
    int bh = blockIdx.x;
    int b = bh >> 4, h = bh & 15;
    int pair = blockIdx.y;
    int wave = threadIdx.x >> 6, lane = threadIdx.x & 63;
    int col = lane & 15, quad = lane >> 4;
    int tile = 2 * pair + (wave >> 2);          // adjacent tiles 2p, 2p+1
    int q0 = tile * 64 + (wave & 3) * 16;

    const __bf16* qbase = qbuf + (size_t)bh * Nseq * HDim;
    const __bf16* kbase = kbuf + (size_t)bh * Nseq * HDim;
    const __bf16* vbase = vt + (size_t)bh * HDim * Nseq;

    bf16x8 aq0 = *reinterpret_cast<const bf16x8*>(qbase + (q0 + col) * HDim + quad * 8);
    bf16x8 aq1 = *reinterpret_cast<const bf16x8*>(qbase + (q0 + col) * HDim + quad * 8 + 32);

    f32x4 o[4] = {};
    float lsum[4] = {0.f, 0.f, 0.f, 0.f};

    int mb = q0 & ~63;                  // the one masked 64-key block for this wave
    int loop_end = 128 * pair + 128;    // covers tile 2p+1's causal range

    // staging indices (thread-invariant across iterations)
    int srow = threadIdx.x >> 3;                      // key (K) / dim (V) row 0..63
    int schunk = (threadIdx.x & 7) ^ (srow & 7);      // swizzled 16B chunk
    const __bf16* ksrc0 = kbase + srow * HDim + schunk * 8;
    const __bf16* vsrc0 = vbase + (size_t)srow * Nseq + schunk * 8;

    // readback swizzle offsets
    int sw0 = ((quad ^ (col & 7)) * 8);
    int sw1 = (((quad + 4) ^ (col & 7)) * 8);

    // prologue: stage block 0 into buffer 0
    load_lds16(ksrc0, &Kb[0][wave * 512]);
    load_lds16(vsrc0, &Vb[0][wave * 512]);
    FENCE;

    int s = 0;
    for (int kb = 0; kb < loop_end; kb += 64) {
        int nkb = kb + 64;
        if (nkb < loop_end) {
            // prefetch block kb+64 into the other buffer
            load_lds16(ksrc0 + nkb * HDim, &Kb[s ^ 1][wave * 512]);
            load_lds16(vsrc0 + nkb, &Vb[s ^ 1][wave * 512]);
            asm volatile("s_waitcnt vmcnt(2)" ::: "memory");  // drain current buf's loads
        } else {
            asm volatile("s_waitcnt vmcnt(0)" ::: "memory");  // last iter: drain all
        }
        BARRIER;   // staging of buffer s visible to all waves

        if (kb <= mb) {
            bool masked = (kb == mb);
            const __bf16* Kcur = Kb[s];
            const __bf16* Vcur = Vb[s];
            // QK^T from LDS K tile
            f32x4 z = {};
            f32x4 sc[4];
#pragma unroll
            for (int g = 0; g < 4; g++) {
                const __bf16* krow = Kcur + (col + 16 * g) * 64;
                bf16x8 k0 = *reinterpret_cast<const bf16x8*>(krow + sw0);
                bf16x8 k1 = *reinterpret_cast<const bf16x8*>(krow + sw1);
                sc[g] = MFMA16(aq0, k0, z);
                sc[g] = MFMA16(aq1, k1, sc[g]);
            }
            // softmax (no-max) + P to LDS
            if (masked) {
#pragma unroll
                for (int g = 0; g < 4; g++) {
#pragma unroll
                    for (int r = 0; r < 4; r++) {
                        int qi = q0 + quad * 4 + r;
                        float p = (kb + col + 16 * g <= qi) ? exp2f(sc[g][r]) : 0.f;
                        lsum[r] += p;
                        plds[wave][quad * 4 + r][col + 16 * g] = (__bf16)p;
                    }
                }
            } else {
#pragma unroll
                for (int g = 0; g < 4; g++) {
#pragma unroll
                    for (int r = 0; r < 4; r++) {
                        float p = exp2f(sc[g][r]);
                        lsum[r] += p;
                        plds[wave][quad * 4 + r][col + 16 * g] = (__bf16)p;
                    }
                }
            }
            bf16x8 pa0 = *reinterpret_cast<const bf16x8*>(&plds[wave][col][quad * 8]);
            bf16x8 pa1 = *reinterpret_cast<const bf16x8*>(&plds[wave][col][32 + quad * 8]);
            // PV from LDS V tile
#pragma unroll
            for (int nt = 0; nt < 4; nt++) {
                const __bf16* vrow = Vcur + (col + 16 * nt) * 64;
                bf16x8 v0 = *reinterpret_cast<const bf16x8*>(vrow + sw0);
                bf16x8 v1 = *reinterpret_cast<const bf16x8*>(vrow + sw1);
                o[nt] = MFMA16(pa0, v0, o[nt]);
                o[nt] = MFMA16(pa1, v1, o[nt]);
            }
        }
        BARRIER;   // all waves done reading buffer s before it is overwritten next iter
        s ^= 1;
    }

    float linv[4];
#pragma unroll
    for (int r = 0; r < 4; r++) {
        float t = lsum[r];
        t += __shfl_xor(t, 1);
        t += __shfl_xor(t, 2);
        t += __shfl_xor(t, 4);
        t += __shfl_xor(t, 8);
        linv[r] = 1.f / t;
    }
#pragma unroll
    for (int nt = 0; nt < 4; nt++) {
#pragma unroll
        for (int r = 0; r < 4; r++) {
            int qi = q0 + quad * 4 + r;
            out[((size_t)(b * Nseq + qi)) * Dm + h * HDim + nt * 16 + col] = o[nt][r] * linv[r];
        }
    }
}

extern "C" void kernel_launch(void* const* d_in, const int* in_sizes, int n_in,
                              void* d_out, int out_size, void* d_ws, size_t ws_size,
                              hipStream_t stream) {
    const float* x = nullptr;
    const float* w = nullptr;
    const float* bias = nullptr;
    for (int i = 0; i < n_in; i++) {
        if (in_sizes[i] == Mrows * Dm) x = (const float*)d_in[i];
        else if (in_sizes[i] == Hh * Dm * F3) w = (const float*)d_in[i];
        else if (in_sizes[i] == Hh * F3) bias = (const float*)d_in[i];
    }
    float* outp = (float*)d_out;

    // ws: wt 6 MB | kbuf 8 | qbuf 8 | vt 8 | xb 8 -> 38 MB
    char* ws = (char*)d_ws;
    __bf16* wt = (__bf16*)(ws);
    __bf16* kbuf = (__bf16*)(ws + 6291456);
    __bf16* qbuf = (__bf16*)(ws + 6291456 + 8388608);
    __bf16* vt = (__bf16*)(ws + 6291456 + 2 * 8388608);
    __bf16* xb = (__bf16*)(ws + 6291456 + 3 * 8388608);

    conv_w_kernel<<<dim3(Dm / 32, F3 / 64, Hh), 256, 0, stream>>>(w, wt);
    if (ws_size >= (size_t)(6291456 + 4 * 8388608)) {
        conv_x_kernel<<<Mrows * Dm / (8 * 256), 256, 0, stream>>>(x, xb);
        gemm_proj<<<dim3(Mrows / 256 * (NC / 256)), 512, 0, stream>>>(xb, wt, bias, kbuf, qbuf, vt);
    } else {
        proj_small<<<dim3(Mrows / 128, Hh), 256, 0, stream>>>(x, wt, bias, kbuf, qbuf, vt);
    }
    attn_kernel<<<dim3(32, 16), 512, 0, stream>>>(qbuf, kbuf, vt, outp);
}

// Round 6
// 159.087 us; speedup vs baseline: 1.1209x; 1.1209x over previous
//
#include <hip/hip_runtime.h>
#include <math.h>

typedef float f32x4 __attribute__((ext_vector_type(4)));
typedef __bf16 bf16x8 __attribute__((ext_vector_type(8)));

#define MFMA16(a, b, c) __builtin_amdgcn_mfma_f32_16x16x32_bf16((a), (b), (c), 0, 0, 0)

constexpr int Bsz = 2, Nseq = 2048, Dm = 1024, Hh = 16, HDim = 64, F3 = 192;
constexpr int Mrows = Bsz * Nseq;   // 4096
constexpr int NC = Hh * F3;         // 3072 output cols
constexpr float QSCALE = 0.125f * 1.4426950408889634f;

__device__ inline void load_lds16(const void* g, void* l) {
    __builtin_amdgcn_global_load_lds((const __attribute__((address_space(1))) void*)g,
                                     (__attribute__((address_space(3))) void*)l, 16, 0, 0);
}

#define FENCE asm volatile("" ::: "memory")
#define BARRIER do { FENCE; __builtin_amdgcn_s_barrier(); FENCE; } while (0)

// ---------------- kernel 0: x fp32 -> bf16 ----------------
__global__ __launch_bounds__(256) void conv_x_kernel(const float* __restrict__ x,
                                                     __bf16* __restrict__ xb) {
    int i = blockIdx.x * 256 + threadIdx.x;
    const float4* xv = reinterpret_cast<const float4*>(x);
    float4 a = xv[2 * i];
    float4 b = xv[2 * i + 1];
    bf16x8 o = {(__bf16)a.x, (__bf16)a.y, (__bf16)a.z, (__bf16)a.w,
                (__bf16)b.x, (__bf16)b.y, (__bf16)b.z, (__bf16)b.w};
    *reinterpret_cast<bf16x8*>(xb + 8 * i) = o;
}

// ---------------- kernel 1: W fp32 [h][d][c] -> bf16 transposed [h][c][d] ----------------
__global__ __launch_bounds__(256) void conv_w_kernel(const float* __restrict__ w,
                                                     __bf16* __restrict__ wt) {
    __shared__ __bf16 tile[32][66];
    int h = blockIdx.z, d0 = blockIdx.x * 32, c0 = blockIdx.y * 64;
    for (int i = threadIdx.x; i < 32 * 64; i += 256) {
        int di = i >> 6, cj = i & 63;
        tile[di][cj] = (__bf16)w[(size_t)(h * Dm + d0 + di) * F3 + c0 + cj];
    }
    __syncthreads();
    for (int i = threadIdx.x; i < 32 * 64; i += 256) {
        int ci = i >> 5, dj = i & 31;
        wt[(size_t)(h * F3 + c0 + ci) * Dm + d0 + dj] = tile[dj][ci];
    }
}

// ---------------- kernel 2a: proj as 256x192 2-phase pipelined GEMM ----------------
// Tile 256x192 so the grid is 16x16 = 256 blocks, covering ALL 256 CUs at
// 1 block/CU (LDS 112 KB) instead of leaving 64 CUs idle at 256x256/192 blocks.
// Schedule is the validated 2-phase counted-vmcnt structure: stage j+2 after
// compute-of-j's trailing barrier; wait vmcnt(7) (7 loads/thread/tile: 4 A + 3 B)
// keeps tile j+1 in flight across the barrier. Swizzle/epilogue logic unchanged.
__global__ __launch_bounds__(512, 2) void gemm_proj(const __bf16* __restrict__ xb,
                                                    const __bf16* __restrict__ wt,
                                                    const float* __restrict__ bias,
                                                    __bf16* __restrict__ kbuf,
                                                    __bf16* __restrict__ qbuf,
                                                    __bf16* __restrict__ vt) {
    __shared__ __align__(16) __bf16 Ab[2][256 * 64];
    __shared__ __align__(16) __bf16 Bb[2][192 * 64];

    int flat = blockIdx.x;                       // 0..255
    int swz = (flat & 7) * 32 + (flat >> 3);     // bijective XCD swizzle (256 = 8*32)
    int bm = swz >> 4, bn = swz & 15;            // 16 x 16 tile grid
    int r0 = bm * 256, n0 = bn * 192;

    int w = threadIdx.x >> 6, lane = threadIdx.x & 63;
    int col = lane & 15, quad = lane >> 4;
    int wm = w >> 2, wn = w & 3;                 // per-wave output 128 x 48

    f32x4 acc[8][3] = {};

    int rl = lane >> 3;
    int cg = ((lane & 7) ^ rl) * 8;              // pre-swizzled source chunk

    // stage K-tile t into slot s: per wave 32 A-rows (4 instrs) + 24 B-rows (3 instrs)
    auto stage = [&](int t, int s) {
#pragma unroll
        for (int i = 0; i < 4; i++) {
            int rowb = w * 32 + i * 8;           // multiple of 8
            load_lds16(xb + (size_t)(r0 + rowb + rl) * Dm + t * 64 + cg,
                       &Ab[s][rowb * 64]);
        }
#pragma unroll
        for (int i = 0; i < 3; i++) {
            int rowb = w * 24 + i * 8;           // multiple of 8
            load_lds16(wt + (size_t)(n0 + rowb + rl) * Dm + t * 64 + cg,
                       &Bb[s][rowb * 64]);
        }
    };

    stage(0, 0);
    stage(1, 1);

    for (int j = 0; j < 16; j++) {
        int s = j & 1;
        // counted wait: tile j's 7 loads landed; tile j+1's 7 stay in flight
        if (j < 15) asm volatile("s_waitcnt vmcnt(7)" ::: "memory");
        else        asm volatile("s_waitcnt vmcnt(0)" ::: "memory");
        BARRIER;

#pragma unroll
        for (int ks = 0; ks < 2; ks++) {
            int cq = ks * 4 + quad;
            bf16x8 af[8], bfr[3];
#pragma unroll
            for (int mt = 0; mt < 8; mt++) {
                int row = wm * 128 + mt * 16 + col;
                af[mt] = *reinterpret_cast<const bf16x8*>(
                    &Ab[s][row * 64 + ((cq ^ (row & 7)) * 8)]);
            }
#pragma unroll
            for (int nt = 0; nt < 3; nt++) {
                int row = wn * 48 + nt * 16 + col;
                bfr[nt] = *reinterpret_cast<const bf16x8*>(
                    &Bb[s][row * 64 + ((cq ^ (row & 7)) * 8)]);
            }
            __builtin_amdgcn_s_setprio(1);
#pragma unroll
            for (int mt = 0; mt < 8; mt++)
#pragma unroll
                for (int nt = 0; nt < 3; nt++)
                    acc[mt][nt] = MFMA16(af[mt], bfr[nt], acc[mt][nt]);
            __builtin_amdgcn_s_setprio(0);
        }

        BARRIER;   // all waves done reading slot s
        if (j + 2 < 16) stage(j + 2, s);
    }

#pragma unroll
    for (int nt = 0; nt < 3; nt++) {
        int g = n0 + wn * 48 + nt * 16 + col;
        int h = g / F3, c = g - h * F3;
        float bv = bias[g];
        bool isq = (c >= 64 && c < 128), isv = (c >= 128);
        int cd = c & 63;
#pragma unroll
        for (int mt = 0; mt < 8; mt++) {
#pragma unroll
            for (int rg = 0; rg < 4; rg++) {
                int r = r0 + wm * 128 + mt * 16 + quad * 4 + rg;
                int b = r >> 11, n = r & (Nseq - 1);
                float v = acc[mt][nt][rg] + bv;
                if (isq) v *= QSCALE;
                size_t bh = (size_t)(b * Hh + h);
                if (isv) vt[(bh * HDim + cd) * Nseq + n] = (__bf16)v;
                else ((isq) ? qbuf : kbuf)[(bh * Nseq + n) * HDim + cd] = (__bf16)v;
            }
        }
    }
}

// ---------------- kernel 2b: fallback proj if ws too small ----------------
__global__ __launch_bounds__(256) void proj_small(const float* __restrict__ x,
                                                  const __bf16* __restrict__ wt,
                                                  const float* __restrict__ bias,
                                                  __bf16* __restrict__ kbuf,
                                                  __bf16* __restrict__ qbuf,
                                                  __bf16* __restrict__ vt) {
    int h = blockIdx.y;
    int wave = threadIdx.x >> 6, lane = threadIdx.x & 63;
    int col = lane & 15, quad = lane >> 4;
    int r0 = blockIdx.x * 128 + wave * 32;

    f32x4 acc[12][2] = {};
    const float* xr0 = x + (size_t)(r0 + col) * Dm + quad * 8;
    const float* xr1 = xr0 + 16 * Dm;
    const __bf16* wbase = wt + (size_t)(h * F3 + col) * Dm + quad * 8;

    for (int k0 = 0; k0 < Dm; k0 += 32) {
        float4 a0lo = *reinterpret_cast<const float4*>(xr0 + k0);
        float4 a0hi = *reinterpret_cast<const float4*>(xr0 + k0 + 4);
        float4 a1lo = *reinterpret_cast<const float4*>(xr1 + k0);
        float4 a1hi = *reinterpret_cast<const float4*>(xr1 + k0 + 4);
        bf16x8 a0 = {(__bf16)a0lo.x, (__bf16)a0lo.y, (__bf16)a0lo.z, (__bf16)a0lo.w,
                     (__bf16)a0hi.x, (__bf16)a0hi.y, (__bf16)a0hi.z, (__bf16)a0hi.w};
        bf16x8 a1 = {(__bf16)a1lo.x, (__bf16)a1lo.y, (__bf16)a1lo.z, (__bf16)a1lo.w,
                     (__bf16)a1hi.x, (__bf16)a1hi.y, (__bf16)a1hi.z, (__bf16)a1hi.w};
#pragma unroll
        for (int ct = 0; ct < 12; ct++) {
            bf16x8 bf = *reinterpret_cast<const bf16x8*>(wbase + ct * 16 * Dm + k0);
            acc[ct][0] = MFMA16(a0, bf, acc[ct][0]);
            acc[ct][1] = MFMA16(a1, bf, acc[ct][1]);
        }
    }
#pragma unroll
    for (int ct = 0; ct < 12; ct++) {
        int c = ct * 16 + col;
        float bv = bias[h * F3 + c];
        int cd = c & 63;
        bool isq = (c >= 64 && c < 128), isv = (c >= 128);
#pragma unroll
        for (int rt = 0; rt < 2; rt++) {
#pragma unroll
            for (int rg = 0; rg < 4; rg++) {
                int r = r0 + rt * 16 + quad * 4 + rg;
                int b = r >> 11, n = r & (Nseq - 1);
                float v = acc[ct][rt][rg] + bv;
                if (isq) v *= QSCALE;
                size_t bh = (size_t)(b * Hh + h);
                if (isv) vt[(bh * HDim + cd) * Nseq + n] = (__bf16)v;
                else ((isq) ? qbuf : kbuf)[(bh * Nseq + n) * HDim + cd] = (__bf16)v;
            }
        }
    }
}

// ---------------- kernel 3: flash attention, 1 q-tile / 4-wave blocks, LPT, 1 barrier ----
// (1) de-paired: each block owns ONE 64-row q-tile with 4 waves; grid (32 bh, 32
// tiles) dispatched heavy-first (tile = 31 - blockIdx.y) for LPT packing. Every
// wave is active every iteration (zero predicated barrier-spinning). LDS 41 KB =>
// 3 blocks/CU = 12 waves/CU (occupancy 21% -> ~37%).
// (2) single barrier per iteration: vmcnt(0) -> barrier -> prefetch(s^1) -> compute(s).
// Race audit: each wave's ds_reads of buffer s are CONSUMED by MFMAs (compiler
// lgkmcnt waits) before that wave reaches the next top-barrier; the overwriting
// global_load_lds of buffer s is issued only after that barrier => no WAR window.
__global__ __launch_bounds__(256) void attn_kernel(const __bf16* __restrict__ qbuf,
                                                   const __bf16* __restrict__ kbuf,
                                                   const __bf16* __restrict__ vt,
                                                   float* __restrict__ out) {
    __shared__ __align__(16) __bf16 Kb[2][64 * 64];    // [buf][key][dim], swizzled chunks
    __shared__ __align__(16) __bf16 Vb[2][64 * 64];    // [buf][dim][key], swizzled chunks
    __shared__ __align__(16) __bf16 plds[4][16][72];   // per-wave P tile
    int bh = blockIdx.x;
    int b = bh >> 4, h = bh & 15;
    int tile = 31 - blockIdx.y;                 // heavy-first (LPT)
    int wave = threadIdx.x >> 6, lane = threadIdx.x & 63;
    int col = lane & 15, quad = lane >> 4;
    int q0 = tile * 64 + wave * 16;

    const __bf16* qbase = qbuf + (size_t)bh * Nseq * HDim;
    const __bf16* kbase = kbuf + (size_t)bh * Nseq * HDim;
    const __bf16* vbase = vt + (size_t)bh * HDim * Nseq;

    bf16x8 aq0 = *reinterpret_cast<const bf16x8*>(qbase + (q0 + col) * HDim + quad * 8);
    bf16x8 aq1 = *reinterpret_cast<const bf16x8*>(qbase + (q0 + col) * HDim + quad * 8 + 32);

    f32x4 o[4] = {};
    float lsum[4] = {0.f, 0.f, 0.f, 0.f};

    int mb = tile * 64;                 // the one masked 64-key block (last iteration)
    int loop_end = mb + 64;

    // staging indices: 4 waves x 2 instrs cover 64 rows; 16B chunk per lane
    int rl = lane >> 3;
    int srow0 = wave * 16 + rl;                       // instr 0 rows
    int srow1 = wave * 16 + 8 + rl;                   // instr 1 rows (same row&7 = rl)
    int sc = (lane & 7) ^ rl;                         // swizzled 16B chunk
    const __bf16* ksrc0 = kbase + srow0 * HDim + sc * 8;
    const __bf16* ksrc1 = kbase + srow1 * HDim + sc * 8;
    const __bf16* vsrc0 = vbase + (size_t)srow0 * Nseq + sc * 8;
    const __bf16* vsrc1 = vbase + (size_t)srow1 * Nseq + sc * 8;
    int d0 = wave * 1024, d1 = wave * 1024 + 512;     // wave-uniform LDS dests

    // readback swizzle offsets
    int sw0 = ((quad ^ (col & 7)) * 8);
    int sw1 = (((quad + 4) ^ (col & 7)) * 8);

    // prologue: stage block 0 into buffer 0
    load_lds16(ksrc0, &Kb[0][d0]);
    load_lds16(ksrc1, &Kb[0][d1]);
    load_lds16(vsrc0, &Vb[0][d0]);
    load_lds16(vsrc1, &Vb[0][d1]);
    FENCE;

    int s = 0;
    for (int kb = 0; kb < loop_end; kb += 64) {
        asm volatile("s_waitcnt vmcnt(0)" ::: "memory");  // drain buffer s's loads
        BARRIER;                                          // staging visible to all waves
        int nkb = kb + 64;
        if (nkb < loop_end) {
            // prefetch next block into the other buffer (drained next iteration)
            load_lds16(ksrc0 + nkb * HDim, &Kb[s ^ 1][d0]);
            load_lds16(ksrc1 + nkb * HDim, &Kb[s ^ 1][d1]);
            load_lds16(vsrc0 + nkb, &Vb[s ^ 1][d0]);
            load_lds16(vsrc1 + nkb, &Vb[s ^ 1][d1]);
        }

        bool masked = (kb == mb);
        const __bf16* Kcur = Kb[s];
        const __bf16* Vcur = Vb[s];
        // QK^T from LDS K tile
        f32x4 z = {};
        f32x4 sc4[4];
#pragma unroll
        for (int g = 0; g < 4; g++) {
            const __bf16* krow = Kcur + (col + 16 * g) * 64;
            bf16x8 k0 = *reinterpret_cast<const bf16x8*>(krow + sw0);
            bf16x8 k1 = *reinterpret_cast<const bf16x8*>(krow + sw1);
            sc4[g] = MFMA16(aq0, k0, z);
            sc4[g] = MFMA16(aq1, k1, sc4[g]);
        }
        // softmax (no-max) + P to LDS
        if (masked) {
#pragma unroll
            for (int g = 0; g < 4; g++) {
#pragma unroll
                for (int r = 0; r < 4; r++) {
                    int qi = q0 + quad * 4 + r;
                    float p = (kb + col + 16 * g <= qi) ? exp2f(sc4[g][r]) : 0.f;
                    lsum[r] += p;
                    plds[wave][quad * 4 + r][col + 16 * g] = (__bf16)p;
                }
            }
        } else {
#pragma unroll
            for (int g = 0; g < 4; g++) {
#pragma unroll
                for (int r = 0; r < 4; r++) {
                    float p = exp2f(sc4[g][r]);
                    lsum[r] += p;
                    plds[wave][quad * 4 + r][col + 16 * g] = (__bf16)p;
                }
            }
        }
        bf16x8 pa0 = *reinterpret_cast<const bf16x8*>(&plds[wave][col][quad * 8]);
        bf16x8 pa1 = *reinterpret_cast<const bf16x8*>(&plds[wave][col][32 + quad * 8]);
        // PV from LDS V tile
#pragma unroll
        for (int nt = 0; nt < 4; nt++) {
            const __bf16* vrow = Vcur + (col + 16 * nt) * 64;
            bf16x8 v0 = *reinterpret_cast<const bf16x8*>(vrow + sw0);
            bf16x8 v1 = *reinterpret_cast<const bf16x8*>(vrow + sw1);
            o[nt] = MFMA16(pa0, v0, o[nt]);
            o[nt] = MFMA16(pa1, v1, o[nt]);
        }
        s ^= 1;
    }

    float linv[4];
#pragma unroll
    for (int r = 0; r < 4; r++) {
        float t = lsum[r];
        t += __shfl_xor(t, 1);
        t += __shfl_xor(t, 2);
        t += __shfl_xor(t, 4);
        t += __shfl_xor(t, 8);
        linv[r] = 1.f / t;
    }
#pragma unroll
    for (int nt = 0; nt < 4; nt++) {
#pragma unroll
        for (int r = 0; r < 4; r++) {
            int qi = q0 + quad * 4 + r;
            out[((size_t)(b * Nseq + qi)) * Dm + h * HDim + nt * 16 + col] = o[nt][r] * linv[r];
        }
    }
}

extern "C" void kernel_launch(void* const* d_in, const int* in_sizes, int n_in,
                              void* d_out, int out_size, void* d_ws, size_t ws_size,
                              hipStream_t stream) {
    const float* x = nullptr;
    const float* w = nullptr;
    const float* bias = nullptr;
    for (int i = 0; i < n_in; i++) {
        if (in_sizes[i] == Mrows * Dm) x = (const float*)d_in[i];
        else if (in_sizes[i] == Hh * Dm * F3) w = (const float*)d_in[i];
        else if (in_sizes[i] == Hh * F3) bias = (const float*)d_in[i];
    }
    float* outp = (float*)d_out;

    // ws: wt 6 MB | kbuf 8 | qbuf 8 | vt 8 | xb 8 -> 38 MB
    char* ws = (char*)d_ws;
    __bf16* wt = (__bf16*)(ws);
    __bf16* kbuf = (__bf16*)(ws + 6291456);
    __bf16* qbuf = (__bf16*)(ws + 6291456 + 8388608);
    __bf16* vt = (__bf16*)(ws + 6291456 + 2 * 8388608);
    __bf16* xb = (__bf16*)(ws + 6291456 + 3 * 8388608);

    conv_w_kernel<<<dim3(Dm / 32, F3 / 64, Hh), 256, 0, stream>>>(w, wt);
    if (ws_size >= (size_t)(6291456 + 4 * 8388608)) {
        conv_x_kernel<<<Mrows * Dm / (8 * 256), 256, 0, stream>>>(x, xb);
        gemm_proj<<<dim3((Mrows / 256) * (NC / 192)), 512, 0, stream>>>(xb, wt, bias, kbuf, qbuf, vt);
    } else {
        proj_small<<<dim3(Mrows / 128, Hh), 256, 0, stream>>>(x, wt, bias, kbuf, qbuf, vt);
    }
    attn_kernel<<<dim3(32, 32), 256, 0, stream>>>(qbuf, kbuf, vt, outp);
}